// Round 15
// baseline (1685.275 us; speedup 1.0000x reference)
//
#include <hip/hip_runtime.h>
#include <stdint.h>

#define T_STEPS 100
#define BATCH   256
#define N_IN    2048
#define N_H     1024
#define N_OUT   10
#define M_TOT   (T_STEPS * BATCH)   // 25600
#define KC      384                 // OpenBLAS SGEMM_DEFAULT_Q (Haswell/Zen)

// ---------------------------------------------------------------------------
// Transpose W1 [N_H][N_IN] -> Bt [N_IN][N_H]. Pure copy, bit-exact.
// ---------------------------------------------------------------------------
__global__ __launch_bounds__(256) void transpose_kernel(
    const float* __restrict__ W, float* __restrict__ Wt) {
  __shared__ float t[32][33];
  const int kb = blockIdx.x * 32, nb = blockIdx.y * 32;
  const int lx = threadIdx.x & 31, ly = threadIdx.x >> 5;  // (32,8)
#pragma unroll
  for (int i = 0; i < 32; i += 8)
    t[ly + i][lx] = W[(size_t)(nb + ly + i) * N_IN + kb + lx];
  __syncthreads();
#pragma unroll
  for (int i = 0; i < 32; i += 8)
    Wt[(size_t)(kb + ly + i) * N_H + nb + lx] = t[lx][ly + i];
}

// ---------------------------------------------------------------------------
// GEMM1 panel pass, B from global (pre-transposed Bt[k][n], L2-resident).
// Bit-exact: per C element each panel is a k-ascending FMA register chain;
// joins = one f32 add per panel boundary (C RMW between dispatches); bias
// after last join. 128x128 tile, BK=16, 256 threads, 8x8 microtile.
// Only A staged in LDS -> LDS bytes/FMA halved vs R14 (the 56%-VALU cap).
// ---------------------------------------------------------------------------
__global__ __launch_bounds__(256, 4) void gemm1_panel_bt(
    const float* __restrict__ A, const float* __restrict__ Bt,
    const float* __restrict__ bias, float* __restrict__ C,
    int ks, int klen, int first, int last) {
  __shared__ float As[16][132];   // [k][m], +4 pad
  const int tid = threadIdx.x;
  const int id = blockIdx.x;
  const int xcd = id & 7;
  const int j = id >> 3;               // 0..199 sequential per XCD
  const int m0 = (xcd * 25 + (j >> 3)) * 128;
  const int n0 = (j & 7) * 128;
  const int tx = tid & 15;        // col group
  const int ty = tid >> 4;        // row group
  const int lrow = tid >> 2;      // 0..63
  const int lc4 = (tid & 3) * 4;  // 0,4,8,12

  float acc[8][8];
#pragma unroll
  for (int i = 0; i < 8; i++)
#pragma unroll
    for (int j2 = 0; j2 < 8; j2++) acc[i][j2] = 0.f;

  const float* Bt1 = &Bt[(size_t)0 * N_H + n0 + tx * 4];
  const float* Bt2 = &Bt[(size_t)0 * N_H + n0 + 64 + tx * 4];

  for (int k0 = ks; k0 < ks + klen; k0 += 16) {
    // stage A tile (128x16)
#pragma unroll
    for (int i = 0; i < 2; i++) {
      const int row = lrow + i * 64;
      const float4 av = *(const float4*)(&A[(size_t)(m0 + row) * N_IN + k0 + lc4]);
      As[lc4 + 0][row] = av.x; As[lc4 + 1][row] = av.y;
      As[lc4 + 2][row] = av.z; As[lc4 + 3][row] = av.w;
    }
    __syncthreads();
#pragma unroll
    for (int k = 0; k < 16; k++) {
      float a[8], b[8];
      *(float4*)&a[0] = *(const float4*)&As[k][ty * 8];
      *(float4*)&a[4] = *(const float4*)&As[k][ty * 8 + 4];
      *(float4*)&b[0] = *(const float4*)&Bt1[(size_t)(k0 + k) * N_H];
      *(float4*)&b[4] = *(const float4*)&Bt2[(size_t)(k0 + k) * N_H];
#pragma unroll
      for (int i = 0; i < 8; i++)
#pragma unroll
        for (int j2 = 0; j2 < 8; j2++)
          acc[i][j2] = __builtin_fmaf(a[i], b[j2], acc[i][j2]);
    }
    __syncthreads();
  }
  // epilogue: join with previous panels (one add), bias after last panel
#pragma unroll
  for (int i = 0; i < 8; i++) {
    const int m = m0 + ty * 8 + i;
    const int n1 = n0 + tx * 4;
    const int n2 = n0 + 64 + tx * 4;
    float4* cp1 = (float4*)&C[(size_t)m * N_H + n1];
    float4* cp2 = (float4*)&C[(size_t)m * N_H + n2];
    float4 v1, v2;
    v1.x = acc[i][0]; v1.y = acc[i][1]; v1.z = acc[i][2]; v1.w = acc[i][3];
    v2.x = acc[i][4]; v2.y = acc[i][5]; v2.z = acc[i][6]; v2.w = acc[i][7];
    if (!first) {
      const float4 o1 = *cp1, o2 = *cp2;
      v1.x = __fadd_rn(o1.x, v1.x); v1.y = __fadd_rn(o1.y, v1.y);
      v1.z = __fadd_rn(o1.z, v1.z); v1.w = __fadd_rn(o1.w, v1.w);
      v2.x = __fadd_rn(o2.x, v2.x); v2.y = __fadd_rn(o2.y, v2.y);
      v2.z = __fadd_rn(o2.z, v2.z); v2.w = __fadd_rn(o2.w, v2.w);
    }
    if (last) {
      v1.x = __fadd_rn(v1.x, bias[n1 + 0]); v1.y = __fadd_rn(v1.y, bias[n1 + 1]);
      v1.z = __fadd_rn(v1.z, bias[n1 + 2]); v1.w = __fadd_rn(v1.w, bias[n1 + 3]);
      v2.x = __fadd_rn(v2.x, bias[n2 + 0]); v2.y = __fadd_rn(v2.y, bias[n2 + 1]);
      v2.z = __fadd_rn(v2.z, bias[n2 + 2]); v2.w = __fadd_rn(v2.w, bias[n2 + 3]);
    }
    *cp1 = v1; *cp2 = v2;
  }
}

// ---------------------------------------------------------------------------
// Fallback (R14 verbatim): both operands via LDS — used if ws lacks Bt room.
// ---------------------------------------------------------------------------
__global__ __launch_bounds__(256, 4) void gemm1_panel(
    const float* __restrict__ A, const float* __restrict__ Bm,
    const float* __restrict__ bias, float* __restrict__ C,
    int ks, int klen, int first, int last) {
  __shared__ float As[16][132];
  __shared__ float Bs[16][132];
  const int tid = threadIdx.x;
  const int id = blockIdx.x;
  const int xcd = id & 7;
  const int j = id >> 3;
  const int m0 = (xcd * 25 + (j >> 3)) * 128;
  const int n0 = (j & 7) * 128;
  const int tx = tid & 15;
  const int ty = tid >> 4;
  const int lrow = tid >> 2;
  const int lc4 = (tid & 3) * 4;

  float acc[8][8];
#pragma unroll
  for (int i = 0; i < 8; i++)
#pragma unroll
    for (int j2 = 0; j2 < 8; j2++) acc[i][j2] = 0.f;

  for (int k0 = ks; k0 < ks + klen; k0 += 16) {
#pragma unroll
    for (int i = 0; i < 2; i++) {
      const int row = lrow + i * 64;
      const float4 av = *(const float4*)(&A[(size_t)(m0 + row) * N_IN + k0 + lc4]);
      As[lc4 + 0][row] = av.x; As[lc4 + 1][row] = av.y;
      As[lc4 + 2][row] = av.z; As[lc4 + 3][row] = av.w;
      const float4 bv = *(const float4*)(&Bm[(size_t)(n0 + row) * N_IN + k0 + lc4]);
      Bs[lc4 + 0][row] = bv.x; Bs[lc4 + 1][row] = bv.y;
      Bs[lc4 + 2][row] = bv.z; Bs[lc4 + 3][row] = bv.w;
    }
    __syncthreads();
#pragma unroll
    for (int k = 0; k < 16; k++) {
      float a[8], b[8];
      *(float4*)&a[0] = *(const float4*)&As[k][ty * 8];
      *(float4*)&a[4] = *(const float4*)&As[k][ty * 8 + 4];
      *(float4*)&b[0] = *(const float4*)&Bs[k][tx * 4];
      *(float4*)&b[4] = *(const float4*)&Bs[k][64 + tx * 4];
#pragma unroll
      for (int i = 0; i < 8; i++)
#pragma unroll
        for (int j2 = 0; j2 < 8; j2++)
          acc[i][j2] = __builtin_fmaf(a[i], b[j2], acc[i][j2]);
    }
    __syncthreads();
  }
#pragma unroll
  for (int i = 0; i < 8; i++) {
    const int m = m0 + ty * 8 + i;
    const int n1 = n0 + tx * 4;
    const int n2 = n0 + 64 + tx * 4;
    float4* cp1 = (float4*)&C[(size_t)m * N_H + n1];
    float4* cp2 = (float4*)&C[(size_t)m * N_H + n2];
    float4 v1, v2;
    v1.x = acc[i][0]; v1.y = acc[i][1]; v1.z = acc[i][2]; v1.w = acc[i][3];
    v2.x = acc[i][4]; v2.y = acc[i][5]; v2.z = acc[i][6]; v2.w = acc[i][7];
    if (!first) {
      const float4 o1 = *cp1, o2 = *cp2;
      v1.x = __fadd_rn(o1.x, v1.x); v1.y = __fadd_rn(o1.y, v1.y);
      v1.z = __fadd_rn(o1.z, v1.z); v1.w = __fadd_rn(o1.w, v1.w);
      v2.x = __fadd_rn(o2.x, v2.x); v2.y = __fadd_rn(o2.y, v2.y);
      v2.z = __fadd_rn(o2.z, v2.z); v2.w = __fadd_rn(o2.w, v2.w);
    }
    if (last) {
      v1.x = __fadd_rn(v1.x, bias[n1 + 0]); v1.y = __fadd_rn(v1.y, bias[n1 + 1]);
      v1.z = __fadd_rn(v1.z, bias[n1 + 2]); v1.w = __fadd_rn(v1.w, bias[n1 + 3]);
      v2.x = __fadd_rn(v2.x, bias[n2 + 0]); v2.y = __fadd_rn(v2.y, bias[n2 + 1]);
      v2.z = __fadd_rn(v2.z, bias[n2 + 2]); v2.w = __fadd_rn(v2.w, bias[n2 + 3]);
    }
    *cp1 = v1; *cp2 = v2;
  }
}

// ---------------------------------------------------------------------------
// Scan1: strict numpy op order (no fma): mem = ((0.9*mem) + cur) - reset.
// ---------------------------------------------------------------------------
__global__ __launch_bounds__(256) void scan1_kernel(
    const float* __restrict__ cur1, unsigned long long* __restrict__ spkbits) {
  const int b = blockIdx.x >> 2;
  const int h = (blockIdx.x & 3) * 256 + threadIdx.x;
  const int lane = threadIdx.x & 63;
  const int word = h >> 6;  // 0..15
  float mem = 0.f;
  for (int t = 0; t < T_STEPS; ++t) {
    const float c = cur1[((size_t)t * BATCH + b) * N_H + h];
    const float reset = (mem > 1.0f) ? 1.0f : 0.0f;   // previous mem
    mem = __fsub_rn(__fadd_rn(__fmul_rn(0.9f, mem), c), reset);
    const unsigned long long msk = __ballot(mem > 1.0f);
    if (lane == 0) spkbits[((size_t)t * BATCH + b) * 16 + word] = msk;
  }
}

// ---------------------------------------------------------------------------
// cur2 (parallel over t,b,o): 3-panel k-ascending FMA chains.
// ---------------------------------------------------------------------------
__global__ __launch_bounds__(256) void cur2_kernel(
    const unsigned long long* __restrict__ spkbits,
    const float* __restrict__ W2, const float* __restrict__ b2,
    float* __restrict__ cur2) {
  const int g = blockIdx.x * 256 + threadIdx.x;   // ((t*256)+b)*10 + o
  const int tb = g / N_OUT;                       // t*256 + b
  const int o = g - tb * N_OUT;
  unsigned long long w[16];
#pragma unroll
  for (int i = 0; i < 16; i++) w[i] = spkbits[(size_t)tb * 16 + i];
  const float* W2o = &W2[(size_t)o * N_H];
  float s1 = 0.f, s2 = 0.f, s3 = 0.f;
#pragma unroll 8
  for (int h = 0; h < KC; ++h) {
    const float spk = ((w[h >> 6] >> (h & 63)) & 1ull) ? 1.0f : 0.0f;
    s1 = __builtin_fmaf(spk, W2o[h], s1);
  }
#pragma unroll 8
  for (int h = KC; h < 2 * KC; ++h) {
    const float spk = ((w[h >> 6] >> (h & 63)) & 1ull) ? 1.0f : 0.0f;
    s2 = __builtin_fmaf(spk, W2o[h], s2);
  }
#pragma unroll 8
  for (int h = 2 * KC; h < N_H; ++h) {
    const float spk = ((w[h >> 6] >> (h & 63)) & 1ull) ? 1.0f : 0.0f;
    s3 = __builtin_fmaf(spk, W2o[h], s3);
  }
  cur2[g] = __fadd_rn(__fadd_rn(__fadd_rn(s1, s2), s3), b2[o]);
}

// ---------------------------------------------------------------------------
// Scan2: strict mem2 scan over t per (b,o); writes spk2 + final mem2 (f32).
// ---------------------------------------------------------------------------
__global__ __launch_bounds__(256) void scan2_kernel(
    const float* __restrict__ cur2, float* __restrict__ out) {
  const int g = blockIdx.x * 256 + threadIdx.x;   // b*10 + o
  float m = 0.f;
  for (int t = 0; t < T_STEPS; ++t) {
    const float c = cur2[(size_t)t * (BATCH * N_OUT) + g];
    const float reset = (m > 1.0f) ? 1.0f : 0.0f;   // previous mem2
    m = __fsub_rn(__fadd_rn(__fmul_rn(0.9f, m), c), reset);
    out[(size_t)t * (BATCH * N_OUT) + g] = (m > 1.0f) ? 1.0f : 0.0f;
  }
  out[(size_t)T_STEPS * (BATCH * N_OUT) + g] = m;
}

// ---------------------------------------------------------------------------
extern "C" void kernel_launch(void* const* d_in, const int* in_sizes, int n_in,
                              void* d_out, int out_size, void* d_ws, size_t ws_size,
                              hipStream_t stream) {
  const float* x  = (const float*)d_in[0];   // [T, B, N_IN]  f32
  const float* W1 = (const float*)d_in[1];   // [N_H, N_IN]   f32
  const float* b1 = (const float*)d_in[2];   // [N_H]         f32
  const float* W2 = (const float*)d_in[3];   // [N_OUT, N_H]  f32
  const float* b2 = (const float*)d_in[4];   // [N_OUT]       f32
  float* out = (float*)d_out;  // f32: spk2[100,256,10] ++ mem2[256,10]

  // ws: cur1 (104.86MB) | bits (3.28MB) | cur2 (1.02MB) | Bt (8.39MB)
  char* p = (char*)d_ws;
  float* cur1 = (float*)p;                           p += (size_t)M_TOT * N_H * 4;
  unsigned long long* bits = (unsigned long long*)p; p += (size_t)M_TOT * 16 * 8;
  float* cur2 = (float*)p;                           p += (size_t)M_TOT * N_OUT * 4;
  float* Bt = (float*)p;                             p += (size_t)N_IN * N_H * 4;

  const int nblk = (M_TOT / 128) * (N_H / 128);   // 1600
  const bool use_bt = ws_size >= (size_t)(p - (char*)d_ws);

  if (use_bt) {
    dim3 tg(N_IN / 32, N_H / 32);
    transpose_kernel<<<tg, 256, 0, stream>>>(W1, Bt);
    for (int ks = 0; ks < N_IN; ks += KC) {
      const int klen = (ks + KC <= N_IN) ? KC : (N_IN - ks);
      gemm1_panel_bt<<<nblk, 256, 0, stream>>>(x, Bt, b1, cur1, ks, klen,
                                               ks == 0 ? 1 : 0,
                                               (ks + klen == N_IN) ? 1 : 0);
    }
  } else {
    for (int ks = 0; ks < N_IN; ks += KC) {
      const int klen = (ks + KC <= N_IN) ? KC : (N_IN - ks);
      gemm1_panel<<<nblk, 256, 0, stream>>>(x, W1, b1, cur1, ks, klen,
                                            ks == 0 ? 1 : 0,
                                            (ks + klen == N_IN) ? 1 : 0);
    }
  }
  scan1_kernel<<<BATCH * (N_H / 256), 256, 0, stream>>>(cur1, bits);
  cur2_kernel<<<(M_TOT * N_OUT) / 256, 256, 0, stream>>>(bits, W2, b2, cur2);
  scan2_kernel<<<(BATCH * N_OUT) / 256, 256, 0, stream>>>(cur2, out);
}

// Round 16
// 1555.725 us; speedup vs baseline: 1.0833x; 1.0833x over previous
//
#include <hip/hip_runtime.h>
#include <stdint.h>

#define T_STEPS 100
#define BATCH   256
#define N_IN    2048
#define N_H     1024
#define N_OUT   10
#define M_TOT   (T_STEPS * BATCH)   // 25600
#define KC      384                 // OpenBLAS SGEMM_DEFAULT_Q (Haswell/Zen)

// ---------------------------------------------------------------------------
// GEMM1 panel pass (one dispatch per KC panel; 6 total), occupancy-maximal.
// Bit-exact contract (same as R9/R14 passing arithmetic): per C element each
// panel is a k-ascending FMA register chain from 0; joins are one f32 add per
// panel boundary in pass order (C RMW between dispatches); bias after last.
// Tile 128m x 64n, BK=16, 256 threads, 8x4 microtile -> ~60 VGPR ->
// __launch_bounds__(256,8) = 32 waves/CU (2x R14's residency).
// Thread (tx,ty): rows ty*8..+7, cols n0+tx*4..+3.
// XCD map: xcd=id&7 owns an m-strip; the 16 n-tiles of one m-tile are
// consecutive on that XCD -> A-slab (196KB) L2-resident, B panel L2-resident.
// ---------------------------------------------------------------------------
__global__ __launch_bounds__(256, 8) void gemm1_panel(
    const float* __restrict__ A, const float* __restrict__ Bm,
    const float* __restrict__ bias, float* __restrict__ C,
    int ks, int klen, int first, int last) {
  __shared__ float As[16][132];   // [k][m], +4 pad
  __shared__ float Bs[16][68];    // [k][n], +4 pad
  const int tid = threadIdx.x;
  const int id = blockIdx.x;
  const int xcd = id & 7;
  const int j = id >> 3;               // 0..399 sequential per XCD
  const int m0 = (xcd * 25 + (j >> 4)) * 128;
  const int n0 = (j & 15) * 64;
  const int tx = tid & 15;        // col group (4 cols)
  const int ty = tid >> 4;        // row group (8 rows)
  const int lrow = tid >> 2;      // 0..63
  const int lc4 = (tid & 3) * 4;  // 0,4,8,12

  float acc[8][4];
#pragma unroll
  for (int i = 0; i < 8; i++)
#pragma unroll
    for (int j2 = 0; j2 < 4; j2++) acc[i][j2] = 0.f;

  for (int k0 = ks; k0 < ks + klen; k0 += 16) {
    // stage A tile (128x16): 2 float4 per thread
#pragma unroll
    for (int i = 0; i < 2; i++) {
      const int row = lrow + i * 64;
      const float4 av = *(const float4*)(&A[(size_t)(m0 + row) * N_IN + k0 + lc4]);
      As[lc4 + 0][row] = av.x; As[lc4 + 1][row] = av.y;
      As[lc4 + 2][row] = av.z; As[lc4 + 3][row] = av.w;
    }
    // stage B tile (64x16): 1 float4 per thread
    {
      const float4 bv = *(const float4*)(&Bm[(size_t)(n0 + lrow) * N_IN + k0 + lc4]);
      Bs[lc4 + 0][lrow] = bv.x; Bs[lc4 + 1][lrow] = bv.y;
      Bs[lc4 + 2][lrow] = bv.z; Bs[lc4 + 3][lrow] = bv.w;
    }
    __syncthreads();
#pragma unroll
    for (int k = 0; k < 16; k++) {
      float a[8], b[4];
      *(float4*)&a[0] = *(const float4*)&As[k][ty * 8];
      *(float4*)&a[4] = *(const float4*)&As[k][ty * 8 + 4];
      *(float4*)&b[0] = *(const float4*)&Bs[k][tx * 4];
#pragma unroll
      for (int i = 0; i < 8; i++)
#pragma unroll
        for (int j2 = 0; j2 < 4; j2++)
          acc[i][j2] = __builtin_fmaf(a[i], b[j2], acc[i][j2]);
    }
    __syncthreads();
  }
  // epilogue: join with previous panels (one add), bias after last panel
#pragma unroll
  for (int i = 0; i < 8; i++) {
    const int m = m0 + ty * 8 + i;
    const int n1 = n0 + tx * 4;
    float4* cp = (float4*)&C[(size_t)m * N_H + n1];
    float4 v;
    v.x = acc[i][0]; v.y = acc[i][1]; v.z = acc[i][2]; v.w = acc[i][3];
    if (!first) {
      const float4 o = *cp;
      v.x = __fadd_rn(o.x, v.x); v.y = __fadd_rn(o.y, v.y);
      v.z = __fadd_rn(o.z, v.z); v.w = __fadd_rn(o.w, v.w);
    }
    if (last) {
      v.x = __fadd_rn(v.x, bias[n1 + 0]); v.y = __fadd_rn(v.y, bias[n1 + 1]);
      v.z = __fadd_rn(v.z, bias[n1 + 2]); v.w = __fadd_rn(v.w, bias[n1 + 3]);
    }
    *cp = v;
  }
}

// ---------------------------------------------------------------------------
// Scan1: strict numpy op order (no fma): mem = ((0.9*mem) + cur) - reset.
// Spikes -> packed 64-bit ballot masks.
// ---------------------------------------------------------------------------
__global__ __launch_bounds__(256) void scan1_kernel(
    const float* __restrict__ cur1, unsigned long long* __restrict__ spkbits) {
  const int b = blockIdx.x >> 2;
  const int h = (blockIdx.x & 3) * 256 + threadIdx.x;
  const int lane = threadIdx.x & 63;
  const int word = h >> 6;  // 0..15
  float mem = 0.f;
  for (int t = 0; t < T_STEPS; ++t) {
    const float c = cur1[((size_t)t * BATCH + b) * N_H + h];
    const float reset = (mem > 1.0f) ? 1.0f : 0.0f;   // previous mem
    mem = __fsub_rn(__fadd_rn(__fmul_rn(0.9f, mem), c), reset);
    const unsigned long long msk = __ballot(mem > 1.0f);
    if (lane == 0) spkbits[((size_t)t * BATCH + b) * 16 + word] = msk;
  }
}

// ---------------------------------------------------------------------------
// cur2 (parallel over t,b,o): 3-panel k-ascending FMA chains —
// s1=[0,384), s2=[384,768), s3=[768,1024); cur2 = ((s1+s2)+s3) + b2[o].
// ---------------------------------------------------------------------------
__global__ __launch_bounds__(256) void cur2_kernel(
    const unsigned long long* __restrict__ spkbits,
    const float* __restrict__ W2, const float* __restrict__ b2,
    float* __restrict__ cur2) {
  const int g = blockIdx.x * 256 + threadIdx.x;   // ((t*256)+b)*10 + o
  const int tb = g / N_OUT;                       // t*256 + b
  const int o = g - tb * N_OUT;
  unsigned long long w[16];
#pragma unroll
  for (int i = 0; i < 16; i++) w[i] = spkbits[(size_t)tb * 16 + i];
  const float* W2o = &W2[(size_t)o * N_H];
  float s1 = 0.f, s2 = 0.f, s3 = 0.f;
#pragma unroll 8
  for (int h = 0; h < KC; ++h) {
    const float spk = ((w[h >> 6] >> (h & 63)) & 1ull) ? 1.0f : 0.0f;
    s1 = __builtin_fmaf(spk, W2o[h], s1);
  }
#pragma unroll 8
  for (int h = KC; h < 2 * KC; ++h) {
    const float spk = ((w[h >> 6] >> (h & 63)) & 1ull) ? 1.0f : 0.0f;
    s2 = __builtin_fmaf(spk, W2o[h], s2);
  }
#pragma unroll 8
  for (int h = 2 * KC; h < N_H; ++h) {
    const float spk = ((w[h >> 6] >> (h & 63)) & 1ull) ? 1.0f : 0.0f;
    s3 = __builtin_fmaf(spk, W2o[h], s3);
  }
  cur2[g] = __fadd_rn(__fadd_rn(__fadd_rn(s1, s2), s3), b2[o]);
}

// ---------------------------------------------------------------------------
// Scan2: strict mem2 scan over t per (b,o); writes spk2 + final mem2 (f32).
// ---------------------------------------------------------------------------
__global__ __launch_bounds__(256) void scan2_kernel(
    const float* __restrict__ cur2, float* __restrict__ out) {
  const int g = blockIdx.x * 256 + threadIdx.x;   // b*10 + o
  float m = 0.f;
  for (int t = 0; t < T_STEPS; ++t) {
    const float c = cur2[(size_t)t * (BATCH * N_OUT) + g];
    const float reset = (m > 1.0f) ? 1.0f : 0.0f;   // previous mem2
    m = __fsub_rn(__fadd_rn(__fmul_rn(0.9f, m), c), reset);
    out[(size_t)t * (BATCH * N_OUT) + g] = (m > 1.0f) ? 1.0f : 0.0f;
  }
  out[(size_t)T_STEPS * (BATCH * N_OUT) + g] = m;
}

// ---------------------------------------------------------------------------
extern "C" void kernel_launch(void* const* d_in, const int* in_sizes, int n_in,
                              void* d_out, int out_size, void* d_ws, size_t ws_size,
                              hipStream_t stream) {
  const float* x  = (const float*)d_in[0];   // [T, B, N_IN]  f32
  const float* W1 = (const float*)d_in[1];   // [N_H, N_IN]   f32
  const float* b1 = (const float*)d_in[2];   // [N_H]         f32
  const float* W2 = (const float*)d_in[3];   // [N_OUT, N_H]  f32
  const float* b2 = (const float*)d_in[4];   // [N_OUT]       f32
  float* out = (float*)d_out;  // f32: spk2[100,256,10] ++ mem2[256,10]

  // ws: cur1 f32 (104.9MB) | bits (3.3MB) | cur2 f32 (1.02MB)
  char* p = (char*)d_ws;
  float* cur1 = (float*)p;                           p += (size_t)M_TOT * N_H * 4;
  unsigned long long* bits = (unsigned long long*)p; p += (size_t)M_TOT * 16 * 8;
  float* cur2 = (float*)p;

  const int nblk = (M_TOT / 128) * (N_H / 64);   // 3200
  for (int ks = 0; ks < N_IN; ks += KC) {
    const int klen = (ks + KC <= N_IN) ? KC : (N_IN - ks);
    gemm1_panel<<<nblk, 256, 0, stream>>>(x, W1, b1, cur1, ks, klen,
                                          ks == 0 ? 1 : 0,
                                          (ks + klen == N_IN) ? 1 : 0);
  }
  scan1_kernel<<<BATCH * (N_H / 256), 256, 0, stream>>>(cur1, bits);
  cur2_kernel<<<(M_TOT * N_OUT) / 256, 256, 0, stream>>>(bits, W2, b2, cur2);
  scan2_kernel<<<(BATCH * N_OUT) / 256, 256, 0, stream>>>(cur2, out);
}